// Round 4
// baseline (168.196 us; speedup 1.0000x reference)
//
#include <hip/hip_runtime.h>
#include <stdint.h>

#define N_       8
#define IC_      16
#define C1_      2048
#define H_       56
#define W_       56
#define THREADS_ 512

typedef float    vf4 __attribute__((ext_vector_type(4)));
typedef uint32_t vu2 __attribute__((ext_vector_type(2)));
typedef int      vi4 __attribute__((ext_vector_type(4)));

__device__ __forceinline__ uint32_t cvt_pk_bf16(float lo, float hi) {
    uint32_t r;
    asm("v_cvt_pk_bf16_f32 %0, %1, %2" : "=v"(r) : "v"(lo), "v"(hi));
    return r;   // r[15:0]=bf16(lo), r[31:16]=bf16(hi), RNE
}

// CLS: 0 = left tile  (w0=0,  16px, left col padded)
//      1 = mid tiles  (w0=16/32, 16px, no padding)
//      2 = right tile (w0=48, 8px, right col padded)
template <int CLS>
__device__ __forceinline__ void body(uint32_t* __restrict__ s1, const int tid,
                                     const int n, const int h, const int w0,
                                     const float* __restrict__ x,
                                     const float* __restrict__ W1,
                                     const float* __restrict__ b1,
                                     const int* __restrict__ idx,
                                     float* __restrict__ out)
{
    constexpr int TW   = (CLS == 2) ? 8 : 16;   // tile width (px)
    constexpr int ROWU = (CLS == 2) ? 6 : 10;   // LDS row stride (dwords)
    constexpr int NV4  = TW / 4;                // float4s per channel tile
    constexpr int WIN  = TW + 2;                // conv window cols

    // ---------------- Phase 1: grouped 3x3 conv -> LDS (bf16 pairs) ----------------
    #pragma unroll 1
    for (int pass = 0; pass < 4; ++pass) {
        const int c  = pass * THREADS_ + tid;              // out1 channel
        const int ci = __builtin_amdgcn_readfirstlane(c >> 7);  // wave-uniform input ch
        const float* xb = x + (size_t)((n * IC_ + ci) * H_) * W_;

        float win[3][WIN];
        #pragma unroll
        for (int rr = 0; rr < 3; ++rr) {
            const int r = h - 1 + rr;
            if ((unsigned)r < (unsigned)H_) {              // uniform branch
                const float* rp = xb + r * W_;
                win[rr][0] = (CLS == 0) ? 0.0f : rp[w0 - 1];
                #pragma unroll
                for (int v = 0; v < NV4; ++v) {
                    const vf4 t = *(const vf4*)(rp + w0 + 4 * v);  // 16B aligned
                    win[rr][1 + 4 * v] = t.x; win[rr][2 + 4 * v] = t.y;
                    win[rr][3 + 4 * v] = t.z; win[rr][4 + 4 * v] = t.w;
                }
                win[rr][WIN - 1] = (CLS == 2) ? 0.0f : rp[w0 + TW];
            } else {
                #pragma unroll
                for (int k = 0; k < WIN; ++k) win[rr][k] = 0.0f;
            }
        }

        float w[9];
        const float* wp = W1 + c * 9;
        #pragma unroll
        for (int k = 0; k < 9; ++k) w[k] = wp[k];
        const float bias = b1[c];

        float acc[TW];
        #pragma unroll
        for (int p = 0; p < TW; ++p) acc[p] = bias;
        #pragma unroll
        for (int dr = 0; dr < 3; ++dr)
            #pragma unroll
            for (int dc = 0; dc < 3; ++dc) {
                const float wk = w[dr * 3 + dc];
                #pragma unroll
                for (int p = 0; p < TW; ++p)
                    acc[p] = fmaf(win[dr][p + dc], wk, acc[p]);
            }

        uint32_t* row = &s1[c * ROWU];                     // even stride -> 8B aligned
        #pragma unroll
        for (int m = 0; m < NV4; ++m) {
            vu2 pr;
            pr.x = cvt_pk_bf16(acc[4 * m + 0], acc[4 * m + 1]);
            pr.y = cvt_pk_bf16(acc[4 * m + 2], acc[4 * m + 3]);
            *(vu2*)(row + 2 * m) = pr;
        }
    }

    __syncthreads();

    // -------- Phase 2: pixel-major gather + max-over-4 + nontemporal float4 stores --------
    constexpr int ITS = (C1_ * NV4) / THREADS_;            // 16 (TW16) or 8 (TW8)
    constexpr int QSH = (NV4 == 4) ? 2 : 1;
    #pragma unroll 4
    for (int it = 0; it < ITS; ++it) {
        const int f = it * THREADS_ + tid;
        const int j = f >> QSH;                            // output channel
        const int q = f & (NV4 - 1);                       // float4 slot in tile
        const vi4 iv = *(const vi4*)(idx + 4 * j);

        const vu2 a = *(const vu2*)(&s1[(iv.x & (C1_ - 1)) * ROWU + 2 * q]);
        const vu2 b = *(const vu2*)(&s1[(iv.y & (C1_ - 1)) * ROWU + 2 * q]);
        const vu2 c = *(const vu2*)(&s1[(iv.z & (C1_ - 1)) * ROWU + 2 * q]);
        const vu2 d = *(const vu2*)(&s1[(iv.w & (C1_ - 1)) * ROWU + 2 * q]);

        #define LO_(u) __uint_as_float((u) << 16)
        #define HI_(u) __uint_as_float((u) & 0xffff0000u)
        vf4 o;
        o.x = fmaxf(fmaxf(LO_(a.x), LO_(b.x)), fmaxf(LO_(c.x), LO_(d.x)));
        o.y = fmaxf(fmaxf(HI_(a.x), HI_(b.x)), fmaxf(HI_(c.x), HI_(d.x)));
        o.z = fmaxf(fmaxf(LO_(a.y), LO_(b.y)), fmaxf(LO_(c.y), LO_(d.y)));
        o.w = fmaxf(fmaxf(HI_(a.y), HI_(b.y)), fmaxf(HI_(c.y), HI_(d.y)));
        #undef LO_
        #undef HI_

        float* op = out + (size_t)(n * C1_ + j) * (H_ * W_) + h * W_ + w0 + 4 * q;
        __builtin_nontemporal_store(o, (vf4*)op);          // 16B aligned
    }
}

__global__ __launch_bounds__(THREADS_, 4)
void rptn_fused(const float* __restrict__ x, const float* __restrict__ W1,
                const float* __restrict__ b1, const int* __restrict__ idx,
                float* __restrict__ out)
{
    __shared__ uint32_t s1[C1_ * 10];                      // 80 KB -> 2 blocks/CU
    const int tid  = threadIdx.x;
    const int b    = blockIdx.x;                           // ((n*56 + h)*4) + wsel
    const int wsel = b & 3;
    const int bh   = b >> 2;
    const int n    = bh / H_;
    const int h    = bh % H_;

    if (wsel == 0)      body<0>(s1, tid, n, h, 0,         x, W1, b1, idx, out);
    else if (wsel == 3) body<2>(s1, tid, n, h, 48,        x, W1, b1, idx, out);
    else                body<1>(s1, tid, n, h, wsel << 4, x, W1, b1, idx, out);
}

extern "C" void kernel_launch(void* const* d_in, const int* in_sizes, int n_in,
                              void* d_out, int out_size, void* d_ws, size_t ws_size,
                              hipStream_t stream)
{
    const float* x   = (const float*)d_in[0];
    const float* W1  = (const float*)d_in[1];
    const float* b1  = (const float*)d_in[2];
    const int* idxp  = (const int*)d_in[3];
    float* out       = (float*)d_out;

    dim3 grid(N_ * H_ * 4);     // 1792 blocks (7 per CU exactly), exact 56px coverage
    dim3 block(THREADS_);
    hipLaunchKernelGGL(rptn_fused, grid, block, 0, stream, x, W1, b1, idxp, out);
}

// Round 5
// 89.106 us; speedup vs baseline: 1.8876x; 1.8876x over previous
//
#include <hip/hip_runtime.h>
#include <stdint.h>

#define N_       8
#define IC_      16
#define C1_      2048
#define H_       56
#define W_       56
#define THREADS_ 512

typedef float vf4 __attribute__((ext_vector_type(4)));

__device__ __forceinline__ uint32_t cvt_pk_bf16(float lo, float hi) {
    uint32_t r;
    asm("v_cvt_pk_bf16_f32 %0, %1, %2" : "=v"(r) : "v"(lo), "v"(hi));
    return r;   // [15:0]=bf16(lo) [31:16]=bf16(hi), RNE
}

// CLS: 0 = w0=0  (16 px, left col padded)
//      1 = w0=16/32 (16 px, interior)
//      2 = w0=48 (8 px, right col padded)
template <int CLS>
__device__ __forceinline__ void body(uint32_t* __restrict__ s1, const int tid,
                                     const int n, const int h, const int w0,
                                     const float* __restrict__ x,
                                     const float* __restrict__ W1,
                                     const float* __restrict__ b1,
                                     const int* __restrict__ idx,
                                     float* __restrict__ out)
{
    constexpr int TW   = (CLS == 2) ? 8 : 16;   // tile width
    constexpr int ROWU = (CLS == 2) ? 5 : 9;    // odd dword stride -> banks spread
    constexpr int ND   = TW / 2;                // packed dwords per row

    // ---- hoist weights + bias for all 4 passes (register-resident) ----
    float w[4][9], bias[4];
    #pragma unroll
    for (int p = 0; p < 4; ++p) {
        const float* wp = W1 + (p * THREADS_ + tid) * 9;
        #pragma unroll
        for (int k = 0; k < 9; ++k) w[p][k] = wp[k];
        bias[p] = b1[p * THREADS_ + tid];
    }

    // ---------------- Phase 1: grouped 3x3 conv -> LDS (bf16 pairs) ----------------
    #pragma unroll
    for (int p = 0; p < 4; ++p) {
        const int c  = p * THREADS_ + tid;
        const int ci = __builtin_amdgcn_readfirstlane(c >> 7);  // wave-uniform
        const float* xb = x + (size_t)((n * IC_ + ci) * H_) * W_;

        float win[3][TW + 2];
        #pragma unroll
        for (int rr = 0; rr < 3; ++rr) {
            const int r = h - 1 + rr;
            if ((unsigned)r < (unsigned)H_) {                   // uniform branch
                const float* rp = xb + r * W_;
                win[rr][0] = (CLS == 0) ? 0.0f : rp[w0 - 1];
                #pragma unroll
                for (int v = 0; v < TW / 4; ++v) {              // 16B-aligned f4 loads
                    const vf4 t = *(const vf4*)(rp + w0 + 4 * v);
                    win[rr][1 + 4*v] = t.x; win[rr][2 + 4*v] = t.y;
                    win[rr][3 + 4*v] = t.z; win[rr][4 + 4*v] = t.w;
                }
                win[rr][TW + 1] = (CLS == 2) ? 0.0f : rp[w0 + TW];
            } else {
                #pragma unroll
                for (int k = 0; k < TW + 2; ++k) win[rr][k] = 0.0f;
            }
        }

        float acc[TW];
        #pragma unroll
        for (int q = 0; q < TW; ++q) acc[q] = bias[p];
        #pragma unroll
        for (int dr = 0; dr < 3; ++dr)
            #pragma unroll
            for (int dc = 0; dc < 3; ++dc) {
                const float wk = w[p][dr * 3 + dc];
                #pragma unroll
                for (int q = 0; q < TW; ++q)
                    acc[q] = fmaf(win[dr][q + dc], wk, acc[q]);
            }

        uint32_t* row = &s1[c * ROWU];
        #pragma unroll
        for (int m = 0; m < ND; ++m)
            row[m] = cvt_pk_bf16(acc[2 * m], acc[2 * m + 1]);
    }

    __syncthreads();

    // ------- Phase 2: channel-major gather + max-over-4 + aligned float4 stores -------
    #pragma unroll
    for (int p = 0; p < 4; ++p) {
        const int j = p * THREADS_ + tid;                  // output channel
        const int4 iv = *(const int4*)(idx + 4 * j);
        const uint32_t* r0 = &s1[(iv.x & (C1_ - 1)) * ROWU];
        const uint32_t* r1 = &s1[(iv.y & (C1_ - 1)) * ROWU];
        const uint32_t* r2 = &s1[(iv.z & (C1_ - 1)) * ROWU];
        const uint32_t* r3 = &s1[(iv.w & (C1_ - 1)) * ROWU];

        #define LO_(u) __uint_as_float((u) << 16)
        #define HI_(u) __uint_as_float((u) & 0xffff0000u)
        float o[TW];
        #pragma unroll
        for (int k = 0; k < ND; ++k) {                     // adjacent reads -> ds_read2_b32
            const uint32_t a = r0[k], b = r1[k], c = r2[k], d = r3[k];
            o[2 * k]     = fmaxf(fmaxf(LO_(a), LO_(b)), fmaxf(LO_(c), LO_(d)));
            o[2 * k + 1] = fmaxf(fmaxf(HI_(a), HI_(b)), fmaxf(HI_(c), HI_(d)));
        }
        #undef LO_
        #undef HI_

        float* op = out + (size_t)(n * C1_ + j) * (H_ * W_) + h * W_ + w0;  // 16B-aligned
        #pragma unroll
        for (int v = 0; v < TW / 4; ++v) {
            vf4 t; t.x = o[4*v]; t.y = o[4*v+1]; t.z = o[4*v+2]; t.w = o[4*v+3];
            *(vf4*)(op + 4 * v) = t;
        }
    }
}

__global__ __launch_bounds__(THREADS_, 4)
void rptn_fused(const float* __restrict__ x, const float* __restrict__ W1,
                const float* __restrict__ b1, const int* __restrict__ idx,
                float* __restrict__ out)
{
    __shared__ uint32_t s1[C1_ * 9];                      // 72 KB -> 2 blocks/CU
    const int tid  = threadIdx.x;
    const int b    = blockIdx.x;                          // ((n*56 + h)*4) + wsel
    const int wsel = b & 3;
    const int bh   = b >> 2;
    const int n    = bh / H_;
    const int h    = bh % H_;

    if (wsel == 0)      body<0>(s1, tid, n, h, 0,         x, W1, b1, idx, out);
    else if (wsel == 3) body<2>(s1, tid, n, h, 48,        x, W1, b1, idx, out);
    else                body<1>(s1, tid, n, h, wsel << 4, x, W1, b1, idx, out);
}

extern "C" void kernel_launch(void* const* d_in, const int* in_sizes, int n_in,
                              void* d_out, int out_size, void* d_ws, size_t ws_size,
                              hipStream_t stream)
{
    const float* x   = (const float*)d_in[0];
    const float* W1  = (const float*)d_in[1];
    const float* b1  = (const float*)d_in[2];
    const int* idxp  = (const int*)d_in[3];
    float* out       = (float*)d_out;

    dim3 grid(N_ * H_ * 4);     // 1792 blocks, exact 56-px coverage
    dim3 block(THREADS_);
    hipLaunchKernelGGL(rptn_fused, grid, block, 0, stream, x, W1, b1, idxp, out);
}